// Round 15
// baseline (218.500 us; speedup 1.0000x reference)
//
#include <hip/hip_runtime.h>

typedef unsigned short u16;
typedef __attribute__((ext_vector_type(8))) short short8v;
typedef __attribute__((ext_vector_type(4))) float floatx4;

#define B_ 16
#define C_ 512
#define N_ 4096
#define K_ 128   // keys

__device__ __forceinline__ float bf2f(u16 u) {
    unsigned int x = ((unsigned int)u) << 16;
    return __builtin_bit_cast(float, x);
}
__device__ __forceinline__ u16 f2bf(float f) {
    unsigned int u = __builtin_bit_cast(unsigned int, f);
    u = u + 0x7FFFu + ((u >> 16) & 1u);
    return (u16)(u >> 16);
}
// async global(16B) -> LDS, wave-uniform dest base + lane*16
__device__ __forceinline__ void gload_lds16(const u16* g, u16* l) {
    __builtin_amdgcn_global_load_lds(
        (const __attribute__((address_space(1))) void*)g,
        (__attribute__((address_space(3))) void*)l, 16, 0, 0);
}

// counted-vmcnt barrier: VMC newest vmem ops stay in flight across the barrier.
#define BARRIER_VM(VMC) do { \
    asm volatile("s_waitcnt vmcnt(" #VMC ") lgkmcnt(0)" ::: "memory"); \
    __builtin_amdgcn_s_barrier(); \
    __builtin_amdgcn_sched_barrier(0); \
} while (0)

// ---------------------------------------------------------------------------
// P0: fp32 -> bf16 converts (y1,y2,wk1,wk2,wv1,wv2) + wq transpose, one launch
// ---------------------------------------------------------------------------
__global__ void conv_all(const float* __restrict__ y1, const float* __restrict__ y2,
                         const float* __restrict__ wk1, const float* __restrict__ wk2,
                         const float* __restrict__ wv1, const float* __restrict__ wv2,
                         const float* __restrict__ wq1, const float* __restrict__ wq2,
                         u16* y1b, u16* y2b, u16* wk1b, u16* wk2b, u16* wv1b, u16* wv2b,
                         u16* wq1t, u16* wq2t) {
    int tid = blockIdx.x * 256 + threadIdx.x;
    const int SY = B_ * K_ * C_;        // 1048576
    const int SWK = 256 * 512;          // 131072
    const int SWV = 512 * 512;          // 262144
    const int SQ = 128 * 512;           // 65536
    int base = 2*SY + 2*SWK + 2*SWV;
    if (tid < base) {
        const float* src; u16* dst; int off;
        if (tid < SY)                 { src = y1;  dst = y1b;  off = tid; }
        else if (tid < 2*SY)          { src = y2;  dst = y2b;  off = tid - SY; }
        else if (tid < 2*SY+SWK)      { src = wk1; dst = wk1b; off = tid - 2*SY; }
        else if (tid < 2*SY+2*SWK)    { src = wk2; dst = wk2b; off = tid - 2*SY - SWK; }
        else if (tid < 2*SY+2*SWK+SWV){ src = wv1; dst = wv1b; off = tid - 2*SY - 2*SWK; }
        else                          { src = wv2; dst = wv2b; off = tid - 2*SY - 2*SWK - SWV; }
        dst[off] = f2bf(src[off]);
    } else {
        int e = tid - base;           // 0 .. 2*SQ-1
        const float* s = (e >= SQ) ? wq2 : wq1;
        u16* d = (e >= SQ) ? wq2t : wq1t;
        e &= (SQ - 1);
        int dd = e >> 9;              // 0..127
        int c = e & 511;              // coalesced read over c
        d[c * 128 + dd] = f2bf(s[dd * 512 + c]);
    }
}

// ---------------------------------------------------------------------------
// P1: k1b/k2b [b][key][256] = y @ wk^T + bk  AND  vt1/vt2 [b][c][128] = (y@wv^T+bv)^T
// ---------------------------------------------------------------------------
__global__ void gemm_gkgv(const u16* __restrict__ y1b, const u16* __restrict__ y2b,
                          const u16* __restrict__ wk1b, const u16* __restrict__ wk2b,
                          const u16* __restrict__ wv1b, const u16* __restrict__ wv2b,
                          const float* __restrict__ bk1, const float* __restrict__ bk2,
                          const float* __restrict__ bv1, const float* __restrict__ bv2,
                          u16* k1b, u16* k2b, u16* vt1, u16* vt2) {
    int l = threadIdx.x;
    int id = blockIdx.x;
    const u16 *A, *Bt; const float* bias; u16* outp;
    int m0, n0, po; bool bias_m;
    if (id < 256) {
        int bx = id & 1, by = (id >> 1) & 3, z = id >> 3;
        int b = z >> 1, which = z & 1;
        A = (which ? y2b : y1b) + (size_t)b * K_ * C_;
        Bt = which ? wk2b : wk1b;
        bias = which ? bk2 : bk1;
        outp = (which ? k2b : k1b) + (size_t)b * K_ * 256;
        m0 = bx * 64; n0 = by * 64; po = 256; bias_m = false;
    } else {
        int id2 = id - 256;
        int bx = id2 & 7, by = (id2 >> 3) & 1, z = id2 >> 4;
        int b = z >> 1, which = z & 1;
        A = which ? wv2b : wv1b;
        Bt = (which ? y2b : y1b) + (size_t)b * K_ * C_;
        bias = which ? bv2 : bv1;
        outp = (which ? vt2 : vt1) + (size_t)b * C_ * K_;
        m0 = bx * 64; n0 = by * 64; po = 128; bias_m = true;
    }
    floatx4 acc[4][4] = {};
    for (int ch = 0; ch < 16; ++ch) {
        int koff = ch * 32 + (l >> 4) * 8;
        short8v a[4], wv[4];
#pragma unroll
        for (int mf = 0; mf < 4; ++mf) a[mf] = *(const short8v*)(A + (size_t)(m0 + mf*16 + (l & 15)) * 512 + koff);
#pragma unroll
        for (int nf = 0; nf < 4; ++nf) wv[nf] = *(const short8v*)(Bt + (size_t)(n0 + nf*16 + (l & 15)) * 512 + koff);
#pragma unroll
        for (int mf = 0; mf < 4; ++mf)
#pragma unroll
            for (int nf = 0; nf < 4; ++nf)
                acc[mf][nf] = __builtin_amdgcn_mfma_f32_16x16x32_bf16(a[mf], wv[nf], acc[mf][nf], 0, 0, 0);
    }
#pragma unroll
    for (int mf = 0; mf < 4; ++mf)
#pragma unroll
        for (int nf = 0; nf < 4; ++nf)
#pragma unroll
            for (int rg = 0; rg < 4; ++rg) {
                int m = m0 + mf*16 + (l >> 4)*4 + rg;
                int n = n0 + nf*16 + (l & 15);
                outp[(size_t)m * po + n] = f2bf(acc[mf][nf][rg] + (bias_m ? bias[m] : bias[n]));
            }
}

// ---------------------------------------------------------------------------
// P2: kd = k1b - k2b (bf16); P2b: ebd = bq_cat . kd_row
// ---------------------------------------------------------------------------
__global__ void kd_sub(const u16* __restrict__ k1b, const u16* __restrict__ k2b,
                       u16* kd) {
    int tid = blockIdx.x * 256 + threadIdx.x;
    kd[tid] = f2bf(bf2f(k1b[tid]) - bf2f(k2b[tid]));
}

__global__ void ebd_k(const u16* __restrict__ kd,
                      const float* __restrict__ bq1, const float* __restrict__ bq2,
                      float* ebd) {
    int tid = blockIdx.x * 256 + threadIdx.x;  // 2048
    const u16* kb = kd + (size_t)tid * 256;
    float s = 0.f;
    for (int d = 0; d < 128; ++d) s += bq1[d] * bf2f(kb[d]);
    for (int d = 0; d < 128; ++d) s += bq2[d] * bf2f(kb[128 + d]);
    ebd[tid] = s;
}

// ---------------------------------------------------------------------------
// P3: kkd1/kkd2 [b][key][512] bf16 = kd_half @ wqt^T (K=128 over d)
// ---------------------------------------------------------------------------
__global__ void gemm_gkk(const u16* __restrict__ kd,
                         const u16* __restrict__ wq1t, const u16* __restrict__ wq2t,
                         u16* kkd1, u16* kkd2) {
    int l = threadIdx.x;
    int z = blockIdx.z; int b = z >> 1; int which = z & 1;
    const u16* A = kd + (size_t)b * K_ * 256 + which * 128;
    const u16* Wt = which ? wq2t : wq1t;
    u16* outp = (which ? kkd2 : kkd1) + (size_t)b * K_ * C_;
    int m0 = blockIdx.x * 64, n0 = blockIdx.y * 64;
    floatx4 acc[4][4] = {};
    for (int ch = 0; ch < 4; ++ch) {
        int koff = ch * 32 + (l >> 4) * 8;
        short8v a[4], wv[4];
#pragma unroll
        for (int mf = 0; mf < 4; ++mf) a[mf] = *(const short8v*)(A + (size_t)(m0 + mf*16 + (l & 15)) * 256 + koff);
#pragma unroll
        for (int nf = 0; nf < 4; ++nf) wv[nf] = *(const short8v*)(Wt + (size_t)(n0 + nf*16 + (l & 15)) * 128 + koff);
#pragma unroll
        for (int mf = 0; mf < 4; ++mf)
#pragma unroll
            for (int nf = 0; nf < 4; ++nf)
                acc[mf][nf] = __builtin_amdgcn_mfma_f32_16x16x32_bf16(a[mf], wv[nf], acc[mf][nf], 0, 0, 0);
    }
#pragma unroll
    for (int mf = 0; mf < 4; ++mf)
#pragma unroll
        for (int nf = 0; nf < 4; ++nf)
#pragma unroll
            for (int rg = 0; rg < 4; ++rg) {
                int m = m0 + mf*16 + (l >> 4)*4 + rg;
                int n = n0 + nf*16 + (l & 15);
                outp[(size_t)m * C_ + n] = f2bf(acc[mf][nf][rg]);
            }
}

// ---------------------------------------------------------------------------
// Fused kernel, 512 threads / 8 waves on the same 128px x 128key tile.
// LDS unchanged (64 KB) -> 2 blocks/CU = 16 waves/CU (was 8). Per-wave state
// halved to fit the 128-VGPR cap of __launch_bounds__(512,4).
// E: wave w owns px w*16..+15, all 128 keys (ed[8]); counted-vmcnt barriers.
// PV: 8 steps of 128 c (wave owns 16 c-rows); vf depth-1 dbuf, rs issued
// before the MFMA cluster (never after it).
// ---------------------------------------------------------------------------
__global__ __launch_bounds__(512, 4)
void fused_attn(const float* __restrict__ x1, const float* __restrict__ x2,
                const u16* __restrict__ kkd1, const u16* __restrict__ kkd2,
                const u16* __restrict__ vt1, const u16* __restrict__ vt2,
                const float* __restrict__ ebd, const float* __restrict__ scale_p,
                float* __restrict__ out1, float* __restrict__ out2) {
    __shared__ u16 smem[32768];                    // 64 KB
    u16* xT[2]  = { smem,         smem + 8192 };   // 2x16 KB [128px][64ch] pair-swizzled
    u16* kkS[2] = { smem + 16384, smem + 24576 };  // 2x16 KB [128key][64ch] (pre-swz src)
    u16* attn_s = smem + 16384;                    // 32 KB [128px][128k], aliases kkS

    int id = blockIdx.x;
    int sw = ((id & 7) << 6) | (id >> 3);   // XCD swizzle, 512 = 8*64 bijective
    int b = sw >> 5;
    int n0 = (sw & 31) * 128;
    int t = threadIdx.x, w = t >> 6, l = t & 63;   // w in [0,8)

    const float* xs[2] = { x1 + (size_t)b * C_ * N_, x2 + (size_t)b * C_ * N_ };
    const u16* kkp[2] = { kkd1 + (size_t)b * K_ * C_, kkd2 + (size_t)b * K_ * C_ };

    floatx4 ed[8] = {};   // wave: px rows w*16.., all 128 keys

    float xA[16], xB[16];

    // x load: thread t covers px row (t&127), channels (t>>7)*16 .. +15
    auto SLOADX = [&](int s, float (&v)[16]) {
        int h = s >> 3, c0 = (s & 7) * 64;
        const float* xp = xs[h] + (size_t)(c0 + (t >> 7) * 16) * N_ + n0 + (t & 127);
#pragma unroll
        for (int j = 0; j < 16; ++j) v[j] = xp[(size_t)j * N_];
    };
    auto SWRITEX = [&](int buf, float (&v)[16]) {
        short8v p0, p1;
#pragma unroll
        for (int j = 0; j < 8; ++j) { p0[j] = (short)f2bf(v[j]); p1[j] = (short)f2bf(v[j + 8]); }
        u16* xb = xT[buf];
        int row = t & 127;
        int g0 = (t >> 7) * 2;
        int k = (row >> 1) & 7;
        *(short8v*)&xb[row * 64 + 8 * (g0 ^ k)] = p0;
        *(short8v*)&xb[row * 64 + 8 * ((g0 + 1) ^ k)] = p1;
    };
    // async kk stage: granule gi = i*512+t; key = gi>>3, gp = gi&7;
    // source granule = gp ^ (key&7)  =>  read at 8*(g^(key&7)) returns granule g.
    auto KLDS = [&](int s, int buf) {
        int h = s >> 3, c0 = (s & 7) * 64;
        const u16* kp = kkp[h] + c0;
#pragma unroll
        for (int i = 0; i < 2; ++i) {
            int gi = i * 512 + t;
            int key = gi >> 3, gp = gi & 7;
            gload_lds16(kp + (size_t)key * 512 + (gp ^ (key & 7)) * 8,
                        &kkS[buf][(i * 512 + w * 64) * 8]);
        }
    };
    auto COMPUTE = [&](int buf) {
        u16* xb = xT[buf]; u16* kb = kkS[buf];
#pragma unroll
        for (int cc = 0; cc < 2; ++cc) {
            int g = cc * 4 + (l >> 4);
            int row = w * 16 + (l & 15);
            short8v a = *(const short8v*)&xb[row * 64 + 8 * (g ^ ((row >> 1) & 7))];
#pragma unroll
            for (int kf = 0; kf < 8; ++kf) {
                int key = kf * 16 + (l & 15);
                short8v bb = *(const short8v*)&kb[key * 64 + 8 * (g ^ (key & 7))];
                ed[kf] = __builtin_amdgcn_mfma_f32_16x16x32_bf16(a, bb, ed[kf], 0, 0, 0);
            }
        }
    };

    // ---- E phase: 16 steps of 64 ch, counted-vmcnt barriers (queue: 2 KLDS + 16 x)
    SLOADX(0, xA); KLDS(0, 0);
    SWRITEX(0, xA);
    SLOADX(1, xB); KLDS(1, 1);
#pragma unroll
    for (int rr = 0; rr < 8; ++rr) {
        int sA = 2 * rr, sB = 2 * rr + 1;
        BARRIER_VM(16);
        if (rr > 0) KLDS(sB, 1);
        COMPUTE(0);
        SWRITEX(1, xB);
        if (sA + 2 <= 15) SLOADX(sA + 2, xA);
        if (rr == 7) { BARRIER_VM(0); }
        else         { BARRIER_VM(16); }
        if (sA + 2 <= 15) KLDS(sA + 2, 0);
        COMPUTE(1);
        if (sB + 1 <= 15) SWRITEX(0, xA);
        if (sB + 2 <= 15) SLOADX(sB + 2, xB);
    }

    // ---- fused softmax over 128 keys of |ediff + ebd| (in-register, wave-local)
    float ebv[8];
#pragma unroll
    for (int kf = 0; kf < 8; ++kf) ebv[kf] = ebd[b * 128 + kf * 16 + (l & 15)];
#pragma unroll
    for (int kf = 0; kf < 8; ++kf)
#pragma unroll
        for (int rg = 0; rg < 4; ++rg)
            ed[kf][rg] = fabsf(ed[kf][rg] + ebv[kf]);

    float m4[4];
#pragma unroll
    for (int rg = 0; rg < 4; ++rg) {
        float m = fmaxf(ed[0][rg], ed[1][rg]);
        m = fmaxf(m, fmaxf(ed[2][rg], ed[3][rg]));
        m = fmaxf(m, fmaxf(ed[4][rg], ed[5][rg]));
        m = fmaxf(m, fmaxf(ed[6][rg], ed[7][rg]));
        m4[rg] = m;
    }
#pragma unroll
    for (int st = 1; st < 16; st <<= 1)
#pragma unroll
        for (int rg = 0; rg < 4; ++rg)
            m4[rg] = fmaxf(m4[rg], __shfl_xor(m4[rg], st));

    float s4[4] = {0.f, 0.f, 0.f, 0.f};
#pragma unroll
    for (int kf = 0; kf < 8; ++kf)
#pragma unroll
        for (int rg = 0; rg < 4; ++rg) {
            float e = __expf(ed[kf][rg] - m4[rg]);
            ed[kf][rg] = e;
            s4[rg] += e;
        }
#pragma unroll
    for (int st = 1; st < 16; st <<= 1)
#pragma unroll
        for (int rg = 0; rg < 4; ++rg)
            s4[rg] += __shfl_xor(s4[rg], st);
#pragma unroll
    for (int rg = 0; rg < 4; ++rg) s4[rg] = 1.0f / s4[rg];

    // ---- publish attn into LDS (kkS region), [px][k] swizzled 16 gran/row
    __syncthreads();                   // all waves done reading kkS
#pragma unroll
    for (int rg = 0; rg < 4; ++rg) {
        int row = w * 16 + (l >> 4) * 4 + rg;
#pragma unroll
        for (int kf = 0; kf < 8; ++kf) {
            int col = kf * 16 + (l & 15);
            attn_s[row * 128 + 8 * ((col >> 3) ^ (row & 15)) + (col & 7)] =
                f2bf(ed[kf][rg] * s4[rg]);
        }
    }
    __syncthreads();

    // ---- PV: 8 steps (2 outputs x 4 chunks of 128 c); wave owns 16 c-rows/step.
    // vf depth-1 register dbuf; rs issued at step top (before the MFMA cluster).
    const float sc = scale_p[0];
    const u16* vts[2] = { vt1 + (size_t)b * C_ * K_, vt2 + (size_t)b * C_ * K_ };
    float* outs[2] = { out1 + (size_t)b * C_ * N_, out2 + (size_t)b * C_ * N_ };

    short8v vfA[4], vfB[4];
    auto LOADVF = [&](int s, short8v (&vf)[4]) {
        int oi = s >> 2, cc = s & 3;
        const u16* vp = vts[oi] + (size_t)(cc * 128 + w * 16 + (l & 15)) * K_ + (l >> 4) * 8;
#pragma unroll
        for (int kc = 0; kc < 4; ++kc) vf[kc] = *(const short8v*)(vp + kc * 32);
    };
    auto COMPPV = [&](int s, short8v (&vf)[4]) {
        int oi = s >> 2, cc = s & 3;
        int cr = cc * 128 + w * 16 + (l >> 4) * 4;
        // rs loads issued FIRST (latency hidden under the 32 MFMAs below)
        float rs[4][8];
        const float* rp = xs[oi] + (size_t)cr * N_ + n0 + (l & 15);
#pragma unroll
        for (int rg = 0; rg < 4; ++rg)
#pragma unroll
            for (int nf = 0; nf < 8; ++nf)
                rs[rg][nf] = rp[(size_t)rg * N_ + nf * 16];
        floatx4 o[8] = {};
#pragma unroll
        for (int kc = 0; kc < 4; ++kc) {
#pragma unroll
            for (int nf = 0; nf < 8; ++nf) {
                int row = nf * 16 + (l & 15);
                int g = kc * 4 + (l >> 4);
                short8v bb = *(const short8v*)&attn_s[row * 128 + 8 * (g ^ (row & 15))];
                o[nf] = __builtin_amdgcn_mfma_f32_16x16x32_bf16(vf[kc], bb, o[nf], 0, 0, 0);
            }
        }
        float* op = outs[oi];
#pragma unroll
        for (int rg = 0; rg < 4; ++rg) {
            size_t rowoff = (size_t)(cr + rg) * N_ + n0 + (l & 15);
#pragma unroll
            for (int nf = 0; nf < 8; ++nf)
                op[rowoff + nf * 16] = sc * o[nf][rg] + rs[rg][nf];
        }
    };

    LOADVF(0, vfA);
    LOADVF(1, vfB);
#pragma unroll
    for (int ss = 0; ss < 4; ++ss) {
        COMPPV(2 * ss, vfA);
        if (2 * ss + 2 < 8) LOADVF(2 * ss + 2, vfA);
        COMPPV(2 * ss + 1, vfB);
        if (2 * ss + 3 < 8) LOADVF(2 * ss + 3, vfB);
    }
}

// ---------------------------------------------------------------------------
extern "C" void kernel_launch(void* const* d_in, const int* in_sizes, int n_in,
                              void* d_out, int out_size, void* d_ws, size_t ws_size,
                              hipStream_t stream) {
    const float* x1 = (const float*)d_in[0];
    const float* y1 = (const float*)d_in[1];
    const float* x2 = (const float*)d_in[2];
    const float* y2 = (const float*)d_in[3];
    const float* wq1 = (const float*)d_in[4];
    const float* bq1 = (const float*)d_in[5];
    const float* wq2 = (const float*)d_in[6];
    const float* bq2 = (const float*)d_in[7];
    const float* wk1 = (const float*)d_in[8];
    const float* bk1 = (const float*)d_in[9];
    const float* wk2 = (const float*)d_in[10];
    const float* bk2 = (const float*)d_in[11];
    const float* wv1 = (const float*)d_in[12];
    const float* bv1 = (const float*)d_in[13];
    const float* wv2 = (const float*)d_in[14];
    const float* bv2 = (const float*)d_in[15];
    const float* scale = (const float*)d_in[16];

    char* ws = (char*)d_ws;
    u16* y1b  = (u16*)(ws + 0);
    u16* y2b  = (u16*)(ws + 2097152);
    u16* wk1b = (u16*)(ws + 4194304);
    u16* wk2b = (u16*)(ws + 4456448);
    u16* wv1b = (u16*)(ws + 4718592);
    u16* wv2b = (u16*)(ws + 5242880);
    u16* wq1t = (u16*)(ws + 5767168);
    u16* wq2t = (u16*)(ws + 5898240);
    u16* k1b  = (u16*)(ws + 6029312);
    u16* k2b  = (u16*)(ws + 7077888);
    u16* kd   = (u16*)(ws + 8126464);
    u16* kkd1 = (u16*)(ws + 9175040);
    u16* kkd2 = (u16*)(ws + 11272192);
    u16* vt1  = (u16*)(ws + 13369344);
    u16* vt2  = (u16*)(ws + 15466496);
    float* ebd = (float*)(ws + 17563648);

    float* out1 = (float*)d_out;
    float* out2 = out1 + (size_t)B_ * C_ * N_;

    hipLaunchKernelGGL(conv_all, dim3(11776), dim3(256), 0, stream,
                       y1, y2, wk1, wk2, wv1, wv2, wq1, wq2,
                       y1b, y2b, wk1b, wk2b, wv1b, wv2b, wq1t, wq2t);
    hipLaunchKernelGGL(gemm_gkgv, dim3(768), dim3(64), 0, stream,
                       y1b, y2b, wk1b, wk2b, wv1b, wv2b, bk1, bk2, bv1, bv2,
                       k1b, k2b, vt1, vt2);
    hipLaunchKernelGGL(kd_sub, dim3(2048), dim3(256), 0, stream, k1b, k2b, kd);
    hipLaunchKernelGGL(ebd_k, dim3(8), dim3(256), 0, stream, kd, bq1, bq2, ebd);
    hipLaunchKernelGGL(gemm_gkk, dim3(2, 8, 32), dim3(64), 0, stream,
                       kd, wq1t, wq2t, kkd1, kkd2);
    hipLaunchKernelGGL(fused_attn, dim3(512), dim3(512), 0, stream,
                       x1, x2, kkd1, kkd2, vt1, vt2, ebd, scale, out1, out2);
}

// Round 16
// 213.213 us; speedup vs baseline: 1.0248x; 1.0248x over previous
//
#include <hip/hip_runtime.h>

typedef unsigned short u16;
typedef __attribute__((ext_vector_type(8))) short short8v;
typedef __attribute__((ext_vector_type(4))) unsigned short ushort4v;
typedef __attribute__((ext_vector_type(4))) float floatx4;

#define B_ 16
#define C_ 512
#define N_ 4096
#define K_ 128   // keys

__device__ __forceinline__ float bf2f(u16 u) {
    unsigned int x = ((unsigned int)u) << 16;
    return __builtin_bit_cast(float, x);
}
__device__ __forceinline__ u16 f2bf(float f) {
    unsigned int u = __builtin_bit_cast(unsigned int, f);
    u = u + 0x7FFFu + ((u >> 16) & 1u);
    return (u16)(u >> 16);
}
// async global(16B) -> LDS, wave-uniform dest base + lane*16
__device__ __forceinline__ void gload_lds16(const u16* g, u16* l) {
    __builtin_amdgcn_global_load_lds(
        (const __attribute__((address_space(1))) void*)g,
        (__attribute__((address_space(3))) void*)l, 16, 0, 0);
}

// counted-vmcnt barrier (R12-proven): 8 newest x loads stay in flight.
#define BARRIER_V8 do { \
    asm volatile("s_waitcnt vmcnt(8) lgkmcnt(0)" ::: "memory"); \
    __builtin_amdgcn_s_barrier(); \
    __builtin_amdgcn_sched_barrier(0); \
} while (0)
#define BARRIER_V0 do { \
    asm volatile("s_waitcnt vmcnt(0) lgkmcnt(0)" ::: "memory"); \
    __builtin_amdgcn_s_barrier(); \
    __builtin_amdgcn_sched_barrier(0); \
} while (0)

// ---------------------------------------------------------------------------
// P0: fp32 -> bf16 converts, x4 vectorized (float4 -> 4xbf16); wq transpose scalar.
// grid 3328 x 256.  vec ranges (in float4 units):
//   y1 [0,262144) y2 [262144,524288) wk1 [524288,557056) wk2 [557056,589824)
//   wv1 [589824,655360) wv2 [655360,720896); then 131072 scalar wq threads.
// ---------------------------------------------------------------------------
__global__ void conv_all(const float* __restrict__ y1, const float* __restrict__ y2,
                         const float* __restrict__ wk1, const float* __restrict__ wk2,
                         const float* __restrict__ wv1, const float* __restrict__ wv2,
                         const float* __restrict__ wq1, const float* __restrict__ wq2,
                         u16* y1b, u16* y2b, u16* wk1b, u16* wk2b, u16* wv1b, u16* wv2b,
                         u16* wq1t, u16* wq2t) {
    int tid = blockIdx.x * 256 + threadIdx.x;
    const int VBASE = 720896;
    if (tid < VBASE) {
        const float* src; u16* dst; int off;   // off in float4 units
        if (tid < 262144)      { src = y1;  dst = y1b;  off = tid; }
        else if (tid < 524288) { src = y2;  dst = y2b;  off = tid - 262144; }
        else if (tid < 557056) { src = wk1; dst = wk1b; off = tid - 524288; }
        else if (tid < 589824) { src = wk2; dst = wk2b; off = tid - 557056; }
        else if (tid < 655360) { src = wv1; dst = wv1b; off = tid - 589824; }
        else                   { src = wv2; dst = wv2b; off = tid - 655360; }
        float4 v = *(const float4*)(src + (size_t)off * 4);
        ushort4v p;
        p[0] = f2bf(v.x); p[1] = f2bf(v.y); p[2] = f2bf(v.z); p[3] = f2bf(v.w);
        *(ushort4v*)(dst + (size_t)off * 4) = p;
    } else {
        int e = tid - VBASE;          // 0 .. 131071
        const float* s = (e >= 65536) ? wq2 : wq1;
        u16* d = (e >= 65536) ? wq2t : wq1t;
        e &= 65535;
        int dd = e >> 9;              // 0..127
        int c = e & 511;              // coalesced read over c
        d[c * 128 + dd] = f2bf(s[dd * 512 + c]);
    }
}

// ---------------------------------------------------------------------------
// P1: k1b/k2b [b][key][256] = y @ wk^T + bk  AND  vt1/vt2 [b][c][128] = (y@wv^T+bv)^T
// ---------------------------------------------------------------------------
__global__ void gemm_gkgv(const u16* __restrict__ y1b, const u16* __restrict__ y2b,
                          const u16* __restrict__ wk1b, const u16* __restrict__ wk2b,
                          const u16* __restrict__ wv1b, const u16* __restrict__ wv2b,
                          const float* __restrict__ bk1, const float* __restrict__ bk2,
                          const float* __restrict__ bv1, const float* __restrict__ bv2,
                          u16* k1b, u16* k2b, u16* vt1, u16* vt2) {
    int l = threadIdx.x;
    int id = blockIdx.x;
    const u16 *A, *Bt; const float* bias; u16* outp;
    int m0, n0, po; bool bias_m;
    if (id < 256) {
        int bx = id & 1, by = (id >> 1) & 3, z = id >> 3;
        int b = z >> 1, which = z & 1;
        A = (which ? y2b : y1b) + (size_t)b * K_ * C_;
        Bt = which ? wk2b : wk1b;
        bias = which ? bk2 : bk1;
        outp = (which ? k2b : k1b) + (size_t)b * K_ * 256;
        m0 = bx * 64; n0 = by * 64; po = 256; bias_m = false;
    } else {
        int id2 = id - 256;
        int bx = id2 & 7, by = (id2 >> 3) & 1, z = id2 >> 4;
        int b = z >> 1, which = z & 1;
        A = which ? wv2b : wv1b;
        Bt = (which ? y2b : y1b) + (size_t)b * K_ * C_;
        bias = which ? bv2 : bv1;
        outp = (which ? vt2 : vt1) + (size_t)b * C_ * K_;
        m0 = bx * 64; n0 = by * 64; po = 128; bias_m = true;
    }
    floatx4 acc[4][4] = {};
    for (int ch = 0; ch < 16; ++ch) {
        int koff = ch * 32 + (l >> 4) * 8;
        short8v a[4], wv[4];
#pragma unroll
        for (int mf = 0; mf < 4; ++mf) a[mf] = *(const short8v*)(A + (size_t)(m0 + mf*16 + (l & 15)) * 512 + koff);
#pragma unroll
        for (int nf = 0; nf < 4; ++nf) wv[nf] = *(const short8v*)(Bt + (size_t)(n0 + nf*16 + (l & 15)) * 512 + koff);
#pragma unroll
        for (int mf = 0; mf < 4; ++mf)
#pragma unroll
            for (int nf = 0; nf < 4; ++nf)
                acc[mf][nf] = __builtin_amdgcn_mfma_f32_16x16x32_bf16(a[mf], wv[nf], acc[mf][nf], 0, 0, 0);
    }
#pragma unroll
    for (int mf = 0; mf < 4; ++mf)
#pragma unroll
        for (int nf = 0; nf < 4; ++nf)
#pragma unroll
            for (int rg = 0; rg < 4; ++rg) {
                int m = m0 + mf*16 + (l >> 4)*4 + rg;
                int n = n0 + nf*16 + (l & 15);
                outp[(size_t)m * po + n] = f2bf(acc[mf][nf][rg] + (bias_m ? bias[m] : bias[n]));
            }
}

// ---------------------------------------------------------------------------
// P2 merged: kkd1/kkd2 [b][key][512] = (k1-k2)_half @ wqt^T  (blocks 0..511)
//            ebd[b*128+key] = bq_cat . (k1-k2)_row           (blocks 512..543)
// kd computed on the fly from k1b/k2b (kd_sub kernel eliminated).
// flat grid 544 x 64
// ---------------------------------------------------------------------------
__global__ void gemm_gkk_ebd(const u16* __restrict__ k1b, const u16* __restrict__ k2b,
                             const u16* __restrict__ wq1t, const u16* __restrict__ wq2t,
                             const float* __restrict__ bq1, const float* __restrict__ bq2,
                             u16* kkd1, u16* kkd2, float* ebd) {
    int l = threadIdx.x;
    int id = blockIdx.x;
    if (id >= 512) {
        int tid = (id - 512) * 64 + l;     // 0..2047: b*128+key
        const u16* kb1 = k1b + (size_t)tid * 256;
        const u16* kb2 = k2b + (size_t)tid * 256;
        float s = 0.f;
        for (int d = 0; d < 128; ++d) s += bq1[d] * (bf2f(kb1[d]) - bf2f(kb2[d]));
        for (int d = 0; d < 128; ++d) s += bq2[d] * (bf2f(kb1[128 + d]) - bf2f(kb2[128 + d]));
        ebd[tid] = s;
        return;
    }
    int bx = id & 1, by = (id >> 1) & 7, z = id >> 4;   // z = b*2+which
    int b = z >> 1, which = z & 1;
    const u16* A1 = k1b + (size_t)b * K_ * 256 + which * 128;
    const u16* A2 = k2b + (size_t)b * K_ * 256 + which * 128;
    const u16* Wt = which ? wq2t : wq1t;
    u16* outp = (which ? kkd2 : kkd1) + (size_t)b * K_ * C_;
    int m0 = bx * 64, n0 = by * 64;
    floatx4 acc[4][4] = {};
    for (int ch = 0; ch < 4; ++ch) {
        int koff = ch * 32 + (l >> 4) * 8;
        short8v a[4], wv[4];
#pragma unroll
        for (int mf = 0; mf < 4; ++mf) {
            size_t ro = (size_t)(m0 + mf*16 + (l & 15)) * 256 + koff;
            short8v s1 = *(const short8v*)(A1 + ro);
            short8v s2 = *(const short8v*)(A2 + ro);
            short8v av;
#pragma unroll
            for (int j = 0; j < 8; ++j)
                av[j] = (short)f2bf(bf2f((u16)s1[j]) - bf2f((u16)s2[j]));
            a[mf] = av;
        }
#pragma unroll
        for (int nf = 0; nf < 4; ++nf) wv[nf] = *(const short8v*)(Wt + (size_t)(n0 + nf*16 + (l & 15)) * 128 + koff);
#pragma unroll
        for (int mf = 0; mf < 4; ++mf)
#pragma unroll
            for (int nf = 0; nf < 4; ++nf)
                acc[mf][nf] = __builtin_amdgcn_mfma_f32_16x16x32_bf16(a[mf], wv[nf], acc[mf][nf], 0, 0, 0);
    }
#pragma unroll
    for (int mf = 0; mf < 4; ++mf)
#pragma unroll
        for (int nf = 0; nf < 4; ++nf)
#pragma unroll
            for (int rg = 0; rg < 4; ++rg) {
                int m = m0 + mf*16 + (l >> 4)*4 + rg;
                int n = n0 + nf*16 + (l & 15);
                outp[(size_t)m * C_ + n] = f2bf(acc[mf][nf][rg]);
            }
}

// ---------------------------------------------------------------------------
// Fused kernel [R14 VERBATIM]: E (counted-vmcnt loop) + in-reg softmax + attn
// in kkS-aliased LDS + PV with depth-1 REGISTER prefetch of vf AND rs.
// grid 512 (16b x 32 px-tiles), block 256 (4 waves), LDS 64 KB, 2 blocks/CU.
// ---------------------------------------------------------------------------
__global__ __launch_bounds__(256, 2)
void fused_attn(const float* __restrict__ x1, const float* __restrict__ x2,
                const u16* __restrict__ kkd1, const u16* __restrict__ kkd2,
                const u16* __restrict__ vt1, const u16* __restrict__ vt2,
                const float* __restrict__ ebd, const float* __restrict__ scale_p,
                float* __restrict__ out1, float* __restrict__ out2) {
    __shared__ u16 smem[32768];                    // 64 KB
    u16* xT[2]  = { smem,         smem + 8192 };   // 2x16 KB [px][ch] swizzled
    u16* kkS[2] = { smem + 16384, smem + 24576 };  // 2x16 KB [key][ch] (pre-swz src)
    u16* attn_s = smem + 16384;                    // 32 KB [px][128k], aliases kkS

    int id = blockIdx.x;
    int sw = ((id & 7) << 6) | (id >> 3);   // XCD swizzle, 512 = 8*64 bijective
    int b = sw >> 5;
    int n0 = (sw & 31) * 128;
    int t = threadIdx.x, w = t >> 6, l = t & 63;

    const float* xs[2] = { x1 + (size_t)b * C_ * N_, x2 + (size_t)b * C_ * N_ };
    const u16* kkp[2] = { kkd1 + (size_t)b * K_ * C_, kkd2 + (size_t)b * K_ * C_ };

    floatx4 ed[2][8] = {};   // wave: px rows w*32+mf*16.., all 128 keys

    float xA0[16], xA1[16], xB0[16], xB1[16];

    auto SLOADX = [&](int s, float (&v0)[16], float (&v1)[16]) {
        int h = s >> 3, c0 = (s & 7) * 64;
        const float* xp = xs[h] + (size_t)(c0 + w * 16) * N_ + n0 + 2 * l;
#pragma unroll
        for (int j = 0; j < 16; ++j) {
            float2 f = *(const float2*)(xp + (size_t)j * N_);
            v0[j] = f.x; v1[j] = f.y;
        }
    };
    auto KLDS = [&](int s, int buf) {
        int h = s >> 3, c0 = (s & 7) * 64;
        const u16* kp = kkp[h] + c0;
#pragma unroll
        for (int i = 0; i < 4; ++i) {
            int gi = i * 256 + t;
            int key = gi >> 3, gp = gi & 7;
            gload_lds16(kp + (size_t)key * 512 + (gp ^ (key & 7)) * 8,
                        &kkS[buf][(i * 256 + w * 64) * 8]);
        }
    };
    auto SWRITEX = [&](int buf, float (&v0)[16], float (&v1)[16]) {
        short8v p00, p01, p10, p11;
#pragma unroll
        for (int j = 0; j < 8; ++j) {
            p00[j] = (short)f2bf(v0[j]);  p01[j] = (short)f2bf(v0[j + 8]);
            p10[j] = (short)f2bf(v1[j]);  p11[j] = (short)f2bf(v1[j + 8]);
        }
        u16* xb = xT[buf];
        int row0 = 2 * l, sz = l & 7;
        *(short8v*)&xb[row0 * 64 + 8 * ((w * 2) ^ sz)] = p00;
        *(short8v*)&xb[row0 * 64 + 8 * ((w * 2 + 1) ^ sz)] = p01;
        *(short8v*)&xb[(row0 + 1) * 64 + 8 * ((w * 2) ^ sz)] = p10;
        *(short8v*)&xb[(row0 + 1) * 64 + 8 * ((w * 2 + 1) ^ sz)] = p11;
    };
    auto COMPUTE = [&](int buf) {
        u16* xb = xT[buf]; u16* kb = kkS[buf];
#pragma unroll
        for (int cc = 0; cc < 2; ++cc) {
            short8v a[2];
#pragma unroll
            for (int mf = 0; mf < 2; ++mf) {
                int row = w * 32 + mf * 16 + (l & 15);
                int g = cc * 4 + (l >> 4);
                a[mf] = *(const short8v*)&xb[row * 64 + 8 * (g ^ ((row >> 1) & 7))];
            }
#pragma unroll
            for (int kf = 0; kf < 8; ++kf) {
                int key = kf * 16 + (l & 15);
                int g = cc * 4 + (l >> 4);
                short8v bb = *(const short8v*)&kb[key * 64 + 8 * (g ^ (key & 7))];
#pragma unroll
                for (int mf = 0; mf < 2; ++mf)
                    ed[mf][kf] = __builtin_amdgcn_mfma_f32_16x16x32_bf16(a[mf], bb, ed[mf][kf], 0, 0, 0);
            }
        }
    };

    // ---- E phase: 16 steps of 64 ch, counted-vmcnt barriers
    SLOADX(0, xA0, xA1); KLDS(0, 0);
    SWRITEX(0, xA0, xA1);
    SLOADX(1, xB0, xB1); KLDS(1, 1);
#pragma unroll
    for (int rr = 0; rr < 8; ++rr) {
        int sA = 2 * rr, sB = 2 * rr + 1;
        BARRIER_V8;
        if (rr > 0) KLDS(sB, 1);
        COMPUTE(0);
        SWRITEX(1, xB0, xB1);
        if (sA + 2 <= 15) SLOADX(sA + 2, xA0, xA1);
        if (rr == 7) { BARRIER_V0; }
        else         { BARRIER_V8; }
        if (sA + 2 <= 15) KLDS(sA + 2, 0);
        COMPUTE(1);
        if (sB + 1 <= 15) SWRITEX(0, xA0, xA1);
        if (sB + 2 <= 15) SLOADX(sB + 2, xB0, xB1);
    }

    // ---- fused softmax over 128 keys of |ediff + ebd| (in-register)
    float ebv[8];
#pragma unroll
    for (int kf = 0; kf < 8; ++kf) ebv[kf] = ebd[b * 128 + kf * 16 + (l & 15)];
#pragma unroll
    for (int mf = 0; mf < 2; ++mf)
#pragma unroll
        for (int kf = 0; kf < 8; ++kf)
#pragma unroll
            for (int rg = 0; rg < 4; ++rg)
                ed[mf][kf][rg] = fabsf(ed[mf][kf][rg] + ebv[kf]);

    float mx[2][4], sm[2][4];
#pragma unroll
    for (int mf = 0; mf < 2; ++mf)
#pragma unroll
        for (int rg = 0; rg < 4; ++rg) {
            float m = fmaxf(ed[mf][0][rg], ed[mf][1][rg]);
            m = fmaxf(m, fmaxf(ed[mf][2][rg], ed[mf][3][rg]));
            m = fmaxf(m, fmaxf(ed[mf][4][rg], ed[mf][5][rg]));
            m = fmaxf(m, fmaxf(ed[mf][6][rg], ed[mf][7][rg]));
            mx[mf][rg] = m;
        }
#pragma unroll
    for (int st = 1; st < 16; st <<= 1)
#pragma unroll
        for (int mf = 0; mf < 2; ++mf)
#pragma unroll
            for (int rg = 0; rg < 4; ++rg)
                mx[mf][rg] = fmaxf(mx[mf][rg], __shfl_xor(mx[mf][rg], st));
#pragma unroll
    for (int mf = 0; mf < 2; ++mf)
#pragma unroll
        for (int rg = 0; rg < 4; ++rg) sm[mf][rg] = 0.f;
#pragma unroll
    for (int mf = 0; mf < 2; ++mf)
#pragma unroll
        for (int kf = 0; kf < 8; ++kf)
#pragma unroll
            for (int rg = 0; rg < 4; ++rg) {
                float e = __expf(ed[mf][kf][rg] - mx[mf][rg]);
                ed[mf][kf][rg] = e;
                sm[mf][rg] += e;
            }
#pragma unroll
    for (int st = 1; st < 16; st <<= 1)
#pragma unroll
        for (int mf = 0; mf < 2; ++mf)
#pragma unroll
            for (int rg = 0; rg < 4; ++rg)
                sm[mf][rg] += __shfl_xor(sm[mf][rg], st);
#pragma unroll
    for (int mf = 0; mf < 2; ++mf)
#pragma unroll
        for (int rg = 0; rg < 4; ++rg) sm[mf][rg] = 1.0f / sm[mf][rg];

    // ---- publish attn into LDS (kkS region), [px][k] swizzled 16 gran/row
    __syncthreads();                   // all waves done reading kkS
#pragma unroll
    for (int mf = 0; mf < 2; ++mf)
#pragma unroll
        for (int rg = 0; rg < 4; ++rg) {
            int row = w * 32 + mf * 16 + (l >> 4) * 4 + rg;
#pragma unroll
            for (int kf = 0; kf < 8; ++kf) {
                int col = kf * 16 + (l & 15);
                attn_s[row * 128 + 8 * ((col >> 3) ^ (row & 15)) + (col & 7)] =
                    f2bf(ed[mf][kf][rg] * sm[mf][rg]);
            }
        }
    __syncthreads();

    // ---- PV: 16 steps (2 outputs x 8 chunks of 64 c); wave owns 16 c-rows/step.
    const float sc = scale_p[0];
    const u16* vts[2] = { vt1 + (size_t)b * C_ * K_, vt2 + (size_t)b * C_ * K_ };
    float* outs[2] = { out1 + (size_t)b * C_ * N_, out2 + (size_t)b * C_ * N_ };

    short8v vfA[4], vfB[4];
    float rsA[4][8], rsB[4][8];
    auto LOADPV = [&](int s, short8v (&vf)[4], float (&rs)[4][8]) {
        int oi = s >> 3, cc = s & 7;
        const u16* vp = vts[oi] + (size_t)(cc * 64 + w * 16 + (l & 15)) * K_ + (l >> 4) * 8;
#pragma unroll
        for (int kc = 0; kc < 4; ++kc) vf[kc] = *(const short8v*)(vp + kc * 32);
        const float* rp = xs[oi] + (size_t)(cc * 64 + w * 16 + (l >> 4) * 4) * N_ + n0 + (l & 15);
#pragma unroll
        for (int rg = 0; rg < 4; ++rg)
#pragma unroll
            for (int nf = 0; nf < 8; ++nf)
                rs[rg][nf] = rp[(size_t)rg * N_ + nf * 16];
    };
    auto COMPPV = [&](int s, short8v (&vf)[4], float (&rs)[4][8]) {
        floatx4 o[8] = {};
#pragma unroll
        for (int kc = 0; kc < 4; ++kc) {
#pragma unroll
            for (int nf = 0; nf < 8; ++nf) {
                int row = nf * 16 + (l & 15);
                int g = kc * 4 + (l >> 4);
                short8v bb = *(const short8v*)&attn_s[row * 128 + 8 * (g ^ (row & 15))];
                o[nf] = __builtin_amdgcn_mfma_f32_16x16x32_bf16(vf[kc], bb, o[nf], 0, 0, 0);
            }
        }
        int oi = s >> 3, cc = s & 7;
        float* op = outs[oi];
        int cr = cc * 64 + w * 16 + (l >> 4) * 4;
#pragma unroll
        for (int rg = 0; rg < 4; ++rg) {
            size_t rowoff = (size_t)(cr + rg) * N_ + n0 + (l & 15);
#pragma unroll
            for (int nf = 0; nf < 8; ++nf)
                op[rowoff + nf * 16] = sc * o[nf][rg] + rs[rg][nf];
        }
    };

    LOADPV(0, vfA, rsA);
    LOADPV(1, vfB, rsB);
#pragma unroll
    for (int ss = 0; ss < 8; ++ss) {
        COMPPV(2 * ss, vfA, rsA);
        if (2 * ss + 2 < 16) LOADPV(2 * ss + 2, vfA, rsA);
        COMPPV(2 * ss + 1, vfB, rsB);
        if (2 * ss + 3 < 16) LOADPV(2 * ss + 3, vfB, rsB);
    }
}

// ---------------------------------------------------------------------------
extern "C" void kernel_launch(void* const* d_in, const int* in_sizes, int n_in,
                              void* d_out, int out_size, void* d_ws, size_t ws_size,
                              hipStream_t stream) {
    const float* x1 = (const float*)d_in[0];
    const float* y1 = (const float*)d_in[1];
    const float* x2 = (const float*)d_in[2];
    const float* y2 = (const float*)d_in[3];
    const float* wq1 = (const float*)d_in[4];
    const float* bq1 = (const float*)d_in[5];
    const float* wq2 = (const float*)d_in[6];
    const float* bq2 = (const float*)d_in[7];
    const float* wk1 = (const float*)d_in[8];
    const float* bk1 = (const float*)d_in[9];
    const float* wk2 = (const float*)d_in[10];
    const float* bk2 = (const float*)d_in[11];
    const float* wv1 = (const float*)d_in[12];
    const float* bv1 = (const float*)d_in[13];
    const float* wv2 = (const float*)d_in[14];
    const float* bv2 = (const float*)d_in[15];
    const float* scale = (const float*)d_in[16];

    char* ws = (char*)d_ws;
    u16* y1b  = (u16*)(ws + 0);
    u16* y2b  = (u16*)(ws + 2097152);
    u16* wk1b = (u16*)(ws + 4194304);
    u16* wk2b = (u16*)(ws + 4456448);
    u16* wv1b = (u16*)(ws + 4718592);
    u16* wv2b = (u16*)(ws + 5242880);
    u16* wq1t = (u16*)(ws + 5767168);
    u16* wq2t = (u16*)(ws + 5898240);
    u16* k1b  = (u16*)(ws + 6029312);
    u16* k2b  = (u16*)(ws + 7077888);
    u16* kkd1 = (u16*)(ws + 9175040);
    u16* kkd2 = (u16*)(ws + 11272192);
    u16* vt1  = (u16*)(ws + 13369344);
    u16* vt2  = (u16*)(ws + 15466496);
    float* ebd = (float*)(ws + 17563648);

    float* out1 = (float*)d_out;
    float* out2 = out1 + (size_t)B_ * C_ * N_;

    hipLaunchKernelGGL(conv_all, dim3(3328), dim3(256), 0, stream,
                       y1, y2, wk1, wk2, wv1, wv2, wq1, wq2,
                       y1b, y2b, wk1b, wk2b, wv1b, wv2b, wq1t, wq2t);
    hipLaunchKernelGGL(gemm_gkgv, dim3(768), dim3(64), 0, stream,
                       y1b, y2b, wk1b, wk2b, wv1b, wv2b, bk1, bk2, bv1, bv2,
                       k1b, k2b, vt1, vt2);
    hipLaunchKernelGGL(gemm_gkk_ebd, dim3(544), dim3(64), 0, stream,
                       k1b, k2b, wq1t, wq2t, bq1, bq2, kkd1, kkd2, ebd);
    hipLaunchKernelGGL(fused_attn, dim3(512), dim3(256), 0, stream,
                       x1, x2, kkd1, kkd2, vt1, vt2, ebd, scale, out1, out2);
}